// Round 6
// baseline (1444.595 us; speedup 1.0000x reference)
//
#include <hip/hip_runtime.h>
#include <math.h>

// Problem constants
#define BB    64
#define SS    512
#define HH    256
#define HH2   512
#define TMAXX 513
#define NTOP  5
#define EPSF  1e-7f

#if defined(__has_builtin)
#if __has_builtin(__builtin_amdgcn_sdot4)
#define HAVE_SDOT4 1
#endif
#endif

__device__ __forceinline__ int dot4i8_(unsigned a, int b, int c) {
#ifdef HAVE_SDOT4
  return __builtin_amdgcn_sdot4((int)a, b, c, false);
#else
  int acc = c;
#pragma unroll
  for (int j = 0; j < 4; ++j) {
    int av = (int)(signed char)(a >> (8 * j));
    int bv = (int)(signed char)(((unsigned)b) >> (8 * j));
    acc += av * bv;
  }
  return acc;
#endif
}

// ws layout:
//  [0, 512KB)     int8 W_hh packed: uint4 at (d*16 + kq4)*1024 + row
//  [1MB, 1MB+8KB) per-gate-row dequant scales, [d*1024 + row]
//  [4MB, 68MB)    hcomb [64 rows][512 steps][512 elems] f32 (lstm out, read-only for attn)

// -------------------------------------------------------------------------
__global__ void init_kernel(const float* __restrict__ Whh_f, const float* __restrict__ Whh_b,
                            uint4* __restrict__ wq, float* __restrict__ scales) {
  int t = blockIdx.x * blockDim.x + threadIdx.x;
  if (t >= 2048) return;
  int d = t >> 10, row = t & 1023;
  const float* src = (d ? Whh_b : Whh_f) + (size_t)row * HH;
  float m = 1e-20f;
  for (int k = 0; k < HH; ++k) m = fmaxf(m, fabsf(src[k]));
  float inv = 127.f / m;
  scales[t] = m * (1.f / 16129.f);
  for (int kq4 = 0; kq4 < 16; ++kq4) {
    unsigned u[4];
#pragma unroll
    for (int w = 0; w < 4; ++w) {
      unsigned uu = 0;
#pragma unroll
      for (int j = 0; j < 4; ++j) {
        float q = rintf(src[kq4 * 16 + w * 4 + j] * inv);
        q = fminf(fmaxf(q, -127.f), 127.f);
        uu |= ((unsigned)(((int)q) & 0xff)) << (8 * j);
      }
      u[w] = uu;
    }
    wq[(size_t)(d * 16 + kq4) * 1024 + row] = make_uint4(u[0], u[1], u[2], u[3]);
  }
}

// -------------------------------------------------------------------------
// LSTM: 128 blocks = (row r = blk>>1, dir d = blk&1), 256 threads.
// Thread e owns ALL FOUR gate rows (i,f,g,o) of element e: 64 uint4 of int8
// weights in VGPRs, no gates-LDS round trip, one barrier/step (double-
// buffered int8 h in LDS). Integer dot math identical to round 5.
__global__ __launch_bounds__(256, 1)
void lstm_kernel(const float* __restrict__ x,
                 const float* __restrict__ wihf, const float* __restrict__ bf,
                 const float* __restrict__ wihb, const float* __restrict__ bb_,
                 const uint4* __restrict__ wq, const float* __restrict__ scales,
                 float* __restrict__ hcomb) {
  const int r = blockIdx.x >> 1;
  const int d = blockIdx.x & 1;
  const int e = threadIdx.x;          // 0..255

  __shared__ float x_lds[SS];         // 2 KB
  __shared__ int   hbuf[2][64];       // double-buffered int8 h (256 each)

  for (int t = e; t < SS; t += 256) x_lds[t] = x[(size_t)r * SS + t];
  if (e < 64) hbuf[0][e] = 0;

  float wih[4], bias[4], sc[4];
#pragma unroll
  for (int g = 0; g < 4; ++g) {
    int row = g * HH + e;
    wih[g]  = d ? wihb[row] : wihf[row];
    bias[g] = d ? bb_[row]  : bf[row];
    sc[g]   = scales[d * 1024 + row];
  }
  uint4 w[4][16];
#pragma unroll
  for (int g = 0; g < 4; ++g) {
    const uint4* wb = wq + (size_t)(d * 16) * 1024 + g * HH + e;
#pragma unroll
    for (int q = 0; q < 16; ++q) w[g][q] = wb[(size_t)q * 1024];
  }
  float c = 0.f;
  float* hout = hcomb + (size_t)r * SS * HH2 + d * HH;
  __syncthreads();

  int cur = 0;
  for (int i = 0; i < SS; ++i) {
    const int4* hp = (const int4*)hbuf[cur];
    int a0 = 0, a1 = 0, a2 = 0, a3 = 0;
#pragma unroll
    for (int q = 0; q < 16; ++q) {
      int4 h4 = hp[q];                       // uniform address -> LDS broadcast
      a0 = dot4i8_(w[0][q].x, h4.x, a0); a0 = dot4i8_(w[0][q].y, h4.y, a0);
      a0 = dot4i8_(w[0][q].z, h4.z, a0); a0 = dot4i8_(w[0][q].w, h4.w, a0);
      a1 = dot4i8_(w[1][q].x, h4.x, a1); a1 = dot4i8_(w[1][q].y, h4.y, a1);
      a1 = dot4i8_(w[1][q].z, h4.z, a1); a1 = dot4i8_(w[1][q].w, h4.w, a1);
      a2 = dot4i8_(w[2][q].x, h4.x, a2); a2 = dot4i8_(w[2][q].y, h4.y, a2);
      a2 = dot4i8_(w[2][q].z, h4.z, a2); a2 = dot4i8_(w[2][q].w, h4.w, a2);
      a3 = dot4i8_(w[3][q].x, h4.x, a3); a3 = dot4i8_(w[3][q].y, h4.y, a3);
      a3 = dot4i8_(w[3][q].z, h4.z, a3); a3 = dot4i8_(w[3][q].w, h4.w, a3);
    }
    float xv = x_lds[d ? (SS - 1 - i) : i];
    float gi = (float)a0 * sc[0] + fmaf(xv, wih[0], bias[0]);
    float gf = (float)a1 * sc[1] + fmaf(xv, wih[1], bias[1]);
    float gg = (float)a2 * sc[2] + fmaf(xv, wih[2], bias[2]);
    float go = (float)a3 * sc[3] + fmaf(xv, wih[3], bias[3]);
    float ig = 1.f / (1.f + expf(-gi));
    float fg = 1.f / (1.f + expf(-gf));
    float og = 1.f / (1.f + expf(-go));
    c = fg * c + ig * tanhf(gg);
    float hn = og * tanhf(c);
    hout[(size_t)i * HH2 + e] = hn;
    ((signed char*)hbuf[cur ^ 1])[e] = (signed char)(int)rintf(hn * 127.f);
    cur ^= 1;
    __syncthreads();
  }
}

// -------------------------------------------------------------------------
// Attention: ONE WAVE per batch row (64 blocks x 64 threads). Lane l owns
// elems A=[4l,4l+4) and B=[256+4l,256+4l+4). All reduction via shfl_xor
// butterfly (bit-identical on every lane) -> every lane redundantly keeps the
// top-5 (value,slot) state and the 5 cached h_new rows in REGISTERS. An index
// evicted from the top-5 never returns, and the inserted row is always the
// just-computed h_new -> no global history reads or writes at all. hc is
// prefetched one step ahead. No __syncthreads anywhere.
__global__ __launch_bounds__(64, 1)
void attn_kernel(const float* __restrict__ w_t, const float* __restrict__ hcomb,
                 float* __restrict__ out) {
  const int b = blockIdx.x;
  const int l = threadIdx.x;          // 0..63
  const float* hrow = hcomb + (size_t)b * SS * HH2;

  __shared__ float tw_l[TMAXX];       // tw[t] history (only for final attn_w)

  const float4 w1a = *(const float4*)(w_t + 4 * l);
  const float4 w1b = *(const float4*)(w_t + HH + 4 * l);
  const float4 w2a = *(const float4*)(w_t + HH2 + 4 * l);
  const float4 w2b = *(const float4*)(w_t + HH2 + HH + 4 * l);

  // top-5 state, redundant on every lane (sorted desc by value)
  float t5v[5] = {0.f, -1e30f, -1e30f, -1e30f, -1e30f};
  int   t5s[5] = {0, 1, 2, 3, 4};
  int   t5cnt  = 1;                   // entry 0 = (t=0, zero row)
  float4 z4 = make_float4(0.f, 0.f, 0.f, 0.f);
  float4 sA0 = z4, sA1 = z4, sA2 = z4, sA3 = z4, sA4 = z4;
  float4 sB0 = z4, sB1 = z4, sB2 = z4, sB3 = z4, sB4 = z4;
  if (l == 0) tw_l[0] = 0.f;

  float4 ha = *(const float4*)(hrow + 4 * l);
  float4 hb = *(const float4*)(hrow + HH + 4 * l);
  float tw5 = 0.f, inv = 0.f;
  float4 aA = z4, aB = z4;

  for (int i = 0; i < SS; ++i) {
    float4 na = z4, nb = z4;
    if (i + 1 < SS) {                 // prefetch next step's hc
      na = *(const float4*)(hrow + (size_t)(i + 1) * HH2 + 4 * l);
      nb = *(const float4*)(hrow + (size_t)(i + 1) * HH2 + HH + 4 * l);
    }
    // ---- per-rank weights (uniform across lanes)
    float wr[5];
    if (i >= NTOP) {
      tw5 = t5v[4];
      float rk0 = fmaxf(t5v[0] - tw5 - EPSF, 0.f);
      float rk1 = fmaxf(t5v[1] - tw5 - EPSF, 0.f);
      float rk2 = fmaxf(t5v[2] - tw5 - EPSF, 0.f);
      float rk3 = fmaxf(t5v[3] - tw5 - EPSF, 0.f);
      inv = 1.f / (rk0 + rk1 + rk2 + rk3 + EPSF);
      wr[0] = rk0 * inv; wr[1] = rk1 * inv; wr[2] = rk2 * inv; wr[3] = rk3 * inv;
      wr[4] = 0.f;
    } else {
      // dense path: weights = s1 + tw[t] over ALL inserted entries
      float s = tanhf(ha.x) * w1a.x + tanhf(ha.y) * w1a.y +
                tanhf(ha.z) * w1a.z + tanhf(ha.w) * w1a.w +
                tanhf(hb.x) * w1b.x + tanhf(hb.y) * w1b.y +
                tanhf(hb.z) * w1b.z + tanhf(hb.w) * w1b.w;
#pragma unroll
      for (int m = 1; m < 64; m <<= 1) s += __shfl_xor(s, m, 64);
#pragma unroll
      for (int k = 0; k < 5; ++k) wr[k] = (k < t5cnt) ? (s + t5v[k]) : 0.f;
    }
    // ---- rank weights -> slot weights (static, branch-free)
    float ws0 = 0.f, ws1 = 0.f, ws2 = 0.f, ws3 = 0.f, ws4 = 0.f;
#pragma unroll
    for (int k = 0; k < 5; ++k) {
      float wv = wr[k]; int s2 = t5s[k];
      ws0 += (s2 == 0) ? wv : 0.f;
      ws1 += (s2 == 1) ? wv : 0.f;
      ws2 += (s2 == 2) ? wv : 0.f;
      ws3 += (s2 == 3) ? wv : 0.f;
      ws4 += (s2 == 4) ? wv : 0.f;
    }
    // ---- attention context from register slot cache
    aA.x = ws0*sA0.x + ws1*sA1.x + ws2*sA2.x + ws3*sA3.x + ws4*sA4.x;
    aA.y = ws0*sA0.y + ws1*sA1.y + ws2*sA2.y + ws3*sA3.y + ws4*sA4.y;
    aA.z = ws0*sA0.z + ws1*sA1.z + ws2*sA2.z + ws3*sA3.z + ws4*sA4.z;
    aA.w = ws0*sA0.w + ws1*sA1.w + ws2*sA2.w + ws3*sA3.w + ws4*sA4.w;
    aB.x = ws0*sB0.x + ws1*sB1.x + ws2*sB2.x + ws3*sB3.x + ws4*sB4.x;
    aB.y = ws0*sB0.y + ws1*sB1.y + ws2*sB2.y + ws3*sB3.y + ws4*sB4.y;
    aB.z = ws0*sB0.z + ws1*sB1.z + ws2*sB2.z + ws3*sB3.z + ws4*sB4.z;
    aB.w = ws0*sB0.w + ws1*sB1.w + ws2*sB2.w + ws3*sB3.w + ws4*sB4.w;
    // ---- h_new and tw[i+1]
    float4 hnA, hnB;
    hnA.x = ha.x + aA.x; hnA.y = ha.y + aA.y; hnA.z = ha.z + aA.z; hnA.w = ha.w + aA.w;
    hnB.x = hb.x + aB.x; hnB.y = hb.y + aB.y; hnB.z = hb.z + aB.z; hnB.w = hb.w + aB.w;
    float v = tanhf(hnA.x) * w2a.x + tanhf(hnA.y) * w2a.y +
              tanhf(hnA.z) * w2a.z + tanhf(hnA.w) * w2a.w +
              tanhf(hnB.x) * w2b.x + tanhf(hnB.y) * w2b.y +
              tanhf(hnB.z) * w2b.z + tanhf(hnB.w) * w2b.w;
#pragma unroll
    for (int m = 1; m < 64; m <<= 1) v += __shfl_xor(v, m, 64);
    if (l == 0) tw_l[i + 1] = v;
    // ---- insert (v, slot) into top-5 (uniform; evicted never returns)
    bool full = (t5cnt >= 5);
    bool ins  = !full || (v > t5v[4]);
    if (ins) {
      int p    = full ? 4 : t5cnt;
      int slot = full ? t5s[4] : t5cnt;
#pragma unroll
      for (int k = 0; k < 5; ++k) if (k == p) { t5v[k] = v; t5s[k] = slot; }
      if (slot == 0)      { sA0 = hnA; sB0 = hnB; }
      else if (slot == 1) { sA1 = hnA; sB1 = hnB; }
      else if (slot == 2) { sA2 = hnA; sB2 = hnB; }
      else if (slot == 3) { sA3 = hnA; sB3 = hnB; }
      else                { sA4 = hnA; sB4 = hnB; }
      if (!full) ++t5cnt;
#pragma unroll
      for (int k = 4; k >= 1; --k) {
        bool sw = (k <= p) && (t5v[k] > t5v[k - 1]);
        float v0 = t5v[k - 1], v1 = t5v[k];
        int   s0 = t5s[k - 1], s1 = t5s[k];
        t5v[k] = sw ? v0 : v1;  t5v[k - 1] = sw ? v1 : v0;
        t5s[k] = sw ? s0 : s1;  t5s[k - 1] = sw ? s1 : s0;
      }
    }
    ha = na; hb = nb;
  }
  // ---- outputs (state from the last step, i = SS-1)
  *(float4*)(out + (size_t)b * HH2 + 4 * l)      = aA;
  *(float4*)(out + (size_t)b * HH2 + HH + 4 * l) = aB;
  float* ow = out + (size_t)BB * HH2 + (size_t)b * SS;
#pragma unroll
  for (int j = 0; j < 8; ++j) {
    int t = j * 64 + l;
    float rr = tw_l[t] - tw5 - EPSF;
    ow[t] = rr > 0.f ? rr * inv : 0.f;
  }
}

// -------------------------------------------------------------------------
extern "C" void kernel_launch(void* const* d_in, const int* in_sizes, int n_in,
                              void* d_out, int out_size, void* d_ws, size_t ws_size,
                              hipStream_t stream) {
  const float* x     = (const float*)d_in[0];
  const float* Wih_f = (const float*)d_in[1];
  const float* Whh_f = (const float*)d_in[2];
  const float* b_f   = (const float*)d_in[3];
  const float* Wih_b = (const float*)d_in[4];
  const float* Whh_b = (const float*)d_in[5];
  const float* b_b   = (const float*)d_in[6];
  const float* w_t   = (const float*)d_in[7];
  float* out = (float*)d_out;

  char* ws = (char*)d_ws;
  uint4*  wq     = (uint4*)ws;                      // 512 KB int8 weights
  float*  scales = (float*)(ws + (1 << 20));        // 8 KB
  float*  hcomb  = (float*)(ws + (4 << 20));        // 64 MB

  init_kernel<<<8, 256, 0, stream>>>(Whh_f, Whh_b, wq, scales);
  lstm_kernel<<<2 * BB, 256, 0, stream>>>(x, Wih_f, b_f, Wih_b, b_b,
                                          wq, scales, hcomb);
  attn_kernel<<<BB, 64, 0, stream>>>(w_t, hcomb, out);
}

// Round 7
// 1223.313 us; speedup vs baseline: 1.1809x; 1.1809x over previous
//
#include <hip/hip_runtime.h>
#include <math.h>

// Problem constants
#define BB    64
#define SS    512
#define HH    256
#define HH2   512
#define TMAXX 513
#define NTOP  5
#define EPSF  1e-7f

#if defined(__has_builtin)
#if __has_builtin(__builtin_amdgcn_sdot4)
#define HAVE_SDOT4 1
#endif
#endif

__device__ __forceinline__ int dot4i8_(unsigned a, int b, int c) {
#ifdef HAVE_SDOT4
  return __builtin_amdgcn_sdot4((int)a, b, c, false);
#else
  int acc = c;
#pragma unroll
  for (int j = 0; j < 4; ++j) {
    int av = (int)(signed char)(a >> (8 * j));
    int bv = (int)(signed char)(((unsigned)b) >> (8 * j));
    acc += av * bv;
  }
  return acc;
#endif
}

// ws layout:
//  [0, 512KB)     int8 W_hh packed: uint4 at (d*16 + kq4)*1024 + row
//  [1MB, 1MB+8KB) per-gate-row dequant scales, [d*1024 + row]
//  [4MB, 68MB)    hcomb [64 rows][512 steps][512 elems] f32 (lstm out, read-only for attn)

// -------------------------------------------------------------------------
__global__ void init_kernel(const float* __restrict__ Whh_f, const float* __restrict__ Whh_b,
                            uint4* __restrict__ wq, float* __restrict__ scales) {
  int t = blockIdx.x * blockDim.x + threadIdx.x;
  if (t >= 2048) return;
  int d = t >> 10, row = t & 1023;
  const float* src = (d ? Whh_b : Whh_f) + (size_t)row * HH;
  float m = 1e-20f;
  for (int k = 0; k < HH; ++k) m = fmaxf(m, fabsf(src[k]));
  float inv = 127.f / m;
  scales[t] = m * (1.f / 16129.f);
  for (int kq4 = 0; kq4 < 16; ++kq4) {
    unsigned u[4];
#pragma unroll
    for (int w = 0; w < 4; ++w) {
      unsigned uu = 0;
#pragma unroll
      for (int j = 0; j < 4; ++j) {
        float q = rintf(src[kq4 * 16 + w * 4 + j] * inv);
        q = fminf(fmaxf(q, -127.f), 127.f);
        uu |= ((unsigned)(((int)q) & 0xff)) << (8 * j);
      }
      u[w] = uu;
    }
    wq[(size_t)(d * 16 + kq4) * 1024 + row] = make_uint4(u[0], u[1], u[2], u[3]);
  }
}

// -------------------------------------------------------------------------
// LSTM: 128 blocks = (row r = blk>>1, dir d = blk&1), 1024 threads = 16 waves
// -> one block fills a CU at 4 waves/SIMD (TLP hides VALU+LDS latency).
// Thread tid owns ONE gate row (gate = tid>>8, elem = tid&255): 16 uint4 of
// int8 weights in VGPRs (64 regs; __launch_bounds__ caps at 128 -> no spill).
// Each thread applies its own gate's nonlinearity before the LDS round trip,
// so transcendentals are spread over all 16 waves. Integer dot order is
// bit-identical to rounds 5/6.
__global__ __launch_bounds__(1024, 4)
void lstm_kernel(const float* __restrict__ x,
                 const float* __restrict__ wihf, const float* __restrict__ bf,
                 const float* __restrict__ wihb, const float* __restrict__ bb_,
                 const uint4* __restrict__ wq, const float* __restrict__ scales,
                 float* __restrict__ hcomb) {
  const int r   = blockIdx.x >> 1;
  const int d   = blockIdx.x & 1;
  const int tid = threadIdx.x;        // gate row 0..1023
  const int gate = tid >> 8;          // 0=i,1=f,2=g,3=o (wave-uniform)
  const int e    = tid & 255;

  __shared__ float x_lds[SS];         // 2 KB
  __shared__ float gact[1024];        // activated gate values, 4 KB
  __shared__ int   hbuf[2][64];       // double-buffered int8 h (256 each)

  for (int t = tid; t < SS; t += 1024) x_lds[t] = x[(size_t)r * SS + t];
  if (tid < 64) hbuf[0][tid] = 0;

  const float wihv = d ? wihb[tid] : wihf[tid];
  const float bv   = d ? bb_[tid]  : bf[tid];
  const float sc   = scales[d * 1024 + tid];

  uint4 w[16];
  {
    const uint4* wb = wq + (size_t)(d * 16) * 1024 + tid;
#pragma unroll
    for (int q = 0; q < 16; ++q) w[q] = wb[(size_t)q * 1024];
  }
  float c = 0.f;                      // cell state (tid < 256 only)
  float* hout = hcomb + (size_t)r * SS * HH2 + d * HH;
  __syncthreads();

  int cur = 0;
  for (int i = 0; i < SS; ++i) {
    const int4* hp = (const int4*)hbuf[cur];
    int a = 0;
#pragma unroll
    for (int q = 0; q < 16; ++q) {
      int4 h4 = hp[q];                // uniform address -> LDS broadcast
      a = dot4i8_(w[q].x, h4.x, a);
      a = dot4i8_(w[q].y, h4.y, a);
      a = dot4i8_(w[q].z, h4.z, a);
      a = dot4i8_(w[q].w, h4.w, a);
    }
    float xv = x_lds[d ? (SS - 1 - i) : i];
    float gv = (float)a * sc + fmaf(xv, wihv, bv);
    gact[tid] = (gate == 2) ? tanhf(gv) : 1.f / (1.f + expf(-gv));
    __syncthreads();
    if (tid < HH) {
      float ig = gact[tid];
      float fg = gact[HH + tid];
      float gg = gact[2 * HH + tid];
      float og = gact[3 * HH + tid];
      c = fg * c + ig * gg;
      float hn = og * tanhf(c);
      hout[(size_t)i * HH2 + tid] = hn;
      ((signed char*)hbuf[cur ^ 1])[tid] = (signed char)(int)rintf(hn * 127.f);
    }
    cur ^= 1;
    __syncthreads();
  }
}

// -------------------------------------------------------------------------
// Attention: 64 blocks x 512 threads (8 waves -> 2 waves/SIMD TLP). Thread e
// owns h element e. Top-5 (value,slot) state is maintained REDUNDANTLY and
// uniformly on every thread (inputs come from LDS-broadcast sums -> bit-
// identical); the 5 cached h_new rows live as 1 float/slot/thread. An evicted
// index never re-enters, and the inserted row is always the just-computed
// h_new -> no history reads/writes. One barrier per steady-state step via
// double-buffered reduction partials. hc prefetched one step ahead.
__global__ __launch_bounds__(512, 1)
void attn_kernel(const float* __restrict__ w_t, const float* __restrict__ hcomb,
                 float* __restrict__ out) {
  const int b = blockIdx.x;
  const int e = threadIdx.x;          // 0..511
  const int lane = e & 63, wv = e >> 6;
  const float* hrow = hcomb + (size_t)b * SS * HH2;

  __shared__ float tw_l[TMAXX];       // tw[t] history (for final attn_w)
  __shared__ float part[2][8];        // double-buffered v-reduction partials
  __shared__ float spart[8];          // s1 partials (dense steps only)

  const float w1e = w_t[e];
  const float w2e = w_t[HH2 + e];

  // replicated top-5 state (sorted desc); slot k caches elem e of that row
  float t5v[5] = {0.f, -1e30f, -1e30f, -1e30f, -1e30f};
  int   t5s[5] = {0, 1, 2, 3, 4};
  int   t5cnt  = 1;                   // entry 0 = (t=0, zero row)
  float c0 = 0.f, c1 = 0.f, c2 = 0.f, c3 = 0.f, c4 = 0.f;
  if (e == 0) tw_l[0] = 0.f;

  float hc = hrow[e];
  float tw5 = 0.f, inv = 0.f, ctx = 0.f;
  int cur = 0;

  for (int i = 0; i < SS; ++i) {
    float hc_next = (i + 1 < SS) ? hrow[(size_t)(i + 1) * HH2 + e] : 0.f;
    // ---- per-rank weights (uniform)
    float wr[5];
    if (i >= NTOP) {
      tw5 = t5v[4];
      float rk0 = fmaxf(t5v[0] - tw5 - EPSF, 0.f);
      float rk1 = fmaxf(t5v[1] - tw5 - EPSF, 0.f);
      float rk2 = fmaxf(t5v[2] - tw5 - EPSF, 0.f);
      float rk3 = fmaxf(t5v[3] - tw5 - EPSF, 0.f);
      inv = 1.f / (rk0 + rk1 + rk2 + rk3 + EPSF);
      wr[0] = rk0 * inv; wr[1] = rk1 * inv; wr[2] = rk2 * inv; wr[3] = rk3 * inv;
      wr[4] = 0.f;
    } else {
      // dense path: s1 = tanh(hc).w1 (extra reduce, 5 steps only)
      float sv = tanhf(hc) * w1e;
#pragma unroll
      for (int m = 32; m >= 1; m >>= 1) sv += __shfl_xor(sv, m, 64);
      if (lane == 0) spart[wv] = sv;
      __syncthreads();
      float s = spart[0] + spart[1] + spart[2] + spart[3] +
                spart[4] + spart[5] + spart[6] + spart[7];
      __syncthreads();
#pragma unroll
      for (int k = 0; k < 5; ++k) wr[k] = (k < t5cnt) ? (s + t5v[k]) : 0.f;
    }
    // ---- rank -> slot weights (uniform, branch-free)
    float ws0 = 0.f, ws1 = 0.f, ws2 = 0.f, ws3 = 0.f, ws4 = 0.f;
#pragma unroll
    for (int k = 0; k < 5; ++k) {
      float wvk = wr[k]; int s2 = t5s[k];
      ws0 += (s2 == 0) ? wvk : 0.f;
      ws1 += (s2 == 1) ? wvk : 0.f;
      ws2 += (s2 == 2) ? wvk : 0.f;
      ws3 += (s2 == 3) ? wvk : 0.f;
      ws4 += (s2 == 4) ? wvk : 0.f;
    }
    // ---- context, h_new, v = tanh(h_new).w2
    ctx = ws0 * c0 + ws1 * c1 + ws2 * c2 + ws3 * c3 + ws4 * c4;
    float hnew = hc + ctx;
    float pv = tanhf(hnew) * w2e;
#pragma unroll
    for (int m = 32; m >= 1; m >>= 1) pv += __shfl_xor(pv, m, 64);
    if (lane == 0) part[cur][wv] = pv;
    __syncthreads();
    float v = part[cur][0] + part[cur][1] + part[cur][2] + part[cur][3] +
              part[cur][4] + part[cur][5] + part[cur][6] + part[cur][7];
    cur ^= 1;
    if (e == 0) tw_l[i + 1] = v;
    // ---- replicated top-5 insert (uniform); update slot cache
    bool full = (t5cnt >= 5);
    bool ins  = !full || (v > t5v[4]);
    if (ins) {
      int p    = full ? 4 : t5cnt;
      int slot = full ? t5s[4] : t5cnt;
#pragma unroll
      for (int k = 0; k < 5; ++k) if (k == p) { t5v[k] = v; t5s[k] = slot; }
      c0 = (slot == 0) ? hnew : c0;
      c1 = (slot == 1) ? hnew : c1;
      c2 = (slot == 2) ? hnew : c2;
      c3 = (slot == 3) ? hnew : c3;
      c4 = (slot == 4) ? hnew : c4;
      if (!full) ++t5cnt;
#pragma unroll
      for (int k = 4; k >= 1; --k) {
        bool sw = (k <= p) && (t5v[k] > t5v[k - 1]);
        float v0 = t5v[k - 1], v1 = t5v[k];
        int   s0 = t5s[k - 1], s1 = t5s[k];
        t5v[k] = sw ? v0 : v1;  t5v[k - 1] = sw ? v1 : v0;
        t5s[k] = sw ? s0 : s1;  t5s[k - 1] = sw ? s1 : s0;
      }
    }
    hc = hc_next;
  }
  // ---- outputs (state from last step i = SS-1, which is sparse)
  out[(size_t)b * HH2 + e] = ctx;
  __syncthreads();
  float rr = tw_l[e] - tw5 - EPSF;
  out[(size_t)BB * HH2 + (size_t)b * SS + e] = rr > 0.f ? rr * inv : 0.f;
}

// -------------------------------------------------------------------------
extern "C" void kernel_launch(void* const* d_in, const int* in_sizes, int n_in,
                              void* d_out, int out_size, void* d_ws, size_t ws_size,
                              hipStream_t stream) {
  const float* x     = (const float*)d_in[0];
  const float* Wih_f = (const float*)d_in[1];
  const float* Whh_f = (const float*)d_in[2];
  const float* b_f   = (const float*)d_in[3];
  const float* Wih_b = (const float*)d_in[4];
  const float* Whh_b = (const float*)d_in[5];
  const float* b_b   = (const float*)d_in[6];
  const float* w_t   = (const float*)d_in[7];
  float* out = (float*)d_out;

  char* ws = (char*)d_ws;
  uint4*  wq     = (uint4*)ws;                      // 512 KB int8 weights
  float*  scales = (float*)(ws + (1 << 20));        // 8 KB
  float*  hcomb  = (float*)(ws + (4 << 20));        // 64 MB

  init_kernel<<<8, 256, 0, stream>>>(Whh_f, Whh_b, wq, scales);
  lstm_kernel<<<2 * BB, 1024, 0, stream>>>(x, Wih_f, b_f, Wih_b, b_b,
                                           wq, scales, hcomb);
  attn_kernel<<<BB, 512, 0, stream>>>(w_t, hcomb, out);
}